// Round 7
// baseline (75.386 us; speedup 1.0000x reference)
//
#include <hip/hip_runtime.h>
#include <math.h>

#define THRESH 0.65f

typedef float f4 __attribute__((ext_vector_type(4)));

// ws float offsets: sim [0, 131072)  32 maps x 4096  (only ws use)

// K1: grid (32 px-chunks of 128, 16 map-pairs) x 256 threads.
// Thread t = (cslice = t>>5 of 8 channel-slices, q = t&31 of 32 float4 px-quads).
// Each feat value is loaded once (float4) and feeds dot(map0), dot(map1), nsq.
__global__ __launch_bounds__(256) void k_sim(const float* __restrict__ feat,
                                             const float* __restrict__ ref,
                                             float* __restrict__ sim) {
    __shared__ float rn0[256], rn1[256];
    __shared__ float red0[256], red1[256];
    __shared__ float den01[2];
    __shared__ __align__(16) f4 pd0[256], pd1[256], pn[256];
    int t = threadIdx.x;
    int m0 = blockIdx.y * 2;

    float v0 = ref[m0 * 256 + t];
    float v1 = ref[(m0 + 1) * 256 + t];
    red0[t] = v0 * v0;
    red1[t] = v1 * v1;
    __syncthreads();
    int wid = t >> 6, lane = t & 63;
    if (wid < 2) {  // wave 0 -> den0, wave 1 -> den1 (shuffle, no barriers)
        const float* src = wid ? red1 : red0;
        float s = src[lane] + src[lane + 64] + src[lane + 128] + src[lane + 192];
        for (int off = 32; off > 0; off >>= 1) s += __shfl_down(s, off);
        if (lane == 0) den01[wid] = sqrtf(s) + 1e-12f;
    }
    __syncthreads();
    rn0[t] = v0 / den01[0];
    rn1[t] = v1 / den01[1];
    __syncthreads();

    int cslice = t >> 5, q = t & 31;
    const f4* fp4 = (const f4*)feat + blockIdx.x * 32 + q;
    const float* r0 = rn0 + cslice * 32;
    const float* r1 = rn1 + cslice * 32;
    f4 d0 = 0.f, d1 = 0.f, nq = 0.f;
#pragma unroll
    for (int i = 0; i < 32; ++i) {
        f4 fv = fp4[(cslice * 32 + i) * 1024];
        d0 += fv * r0[i];
        d1 += fv * r1[i];
        nq += fv * fv;
    }
    pd0[t] = d0; pd1[t] = d1; pn[t] = nq;
    __syncthreads();
    if (t < 32) {  // sum 8 channel-slices per px-quad, normalize, write both maps
        f4 D0 = pd0[t], D1 = pd1[t], NQ = pn[t];
#pragma unroll
        for (int s = 1; s < 8; ++s) {
            D0 += pd0[s * 32 + t];
            D1 += pd1[s * 32 + t];
            NQ += pn[s * 32 + t];
        }
        f4 dn;
        dn.x = sqrtf(NQ.x) + 1e-12f;
        dn.y = sqrtf(NQ.y) + 1e-12f;
        dn.z = sqrtf(NQ.z) + 1e-12f;
        dn.w = sqrtf(NQ.w) + 1e-12f;
        f4* so = (f4*)sim;
        so[m0 * 1024 + blockIdx.x * 32 + t] = D0 / dn;
        so[(m0 + 1) * 1024 + blockIdx.x * 32 + t] = D1 / dn;
    }
}

// K2: 32 blocks (one per map) x 256 threads (thread = cell).
// 2D segment-corner evaluation: v is bilinear within each (y-seg x x-seg)
// rectangle (exact dyadic weights), so extrema are at the 4 corners. Corners
// are evaluated with the reference's own per-sample formula (y-combine then
// x-combine, single-tap clamp passthrough). Candidates visited in global
// row-major order with strict compares -> first-occurrence tie semantics.
__global__ __launch_bounds__(256) void k_scan_out(const float* __restrict__ sim,
                                                  float* __restrict__ out) {
    __shared__ float S[64 * 65];   // sim map, stride 65 (bank pad)
    __shared__ __align__(16) float sc[256];
    __shared__ float wmin[4];
    __shared__ int wmini[4];

    int m = blockIdx.x, t = threadIdx.x;
    const f4* sm4 = (const f4*)(sim + m * 4096);
#pragma unroll
    for (int k = 0; k < 4; ++k) {
        int fi = k * 256 + t;            // float4 index 0..1023
        f4 v = sm4[fi];
        float* dst = S + (fi >> 4) * 65 + (fi & 15) * 4;
        dst[0] = v.x; dst[1] = v.y; dst[2] = v.z; dst[3] = v.w;
    }
    __syncthreads();

    int cy = t >> 4, cx = t & 15;
    int gxs[6];
#pragma unroll
    for (int j = 0; j < 6; ++j) {
        int g = 4 * cx - 1 + j;
        gxs[j] = min(max(g, 0), 63);
    }
    const int   L0[5]  = {0, 8, 24, 40, 56};
    const int   L1[5]  = {7, 23, 39, 55, 63};
    const float WXA[5] = {0.53125f, 0.03125f, 0.03125f, 0.03125f, 0.03125f};
    const float WXB[5] = {0.96875f, 0.96875f, 0.96875f, 0.96875f, 0.46875f};
    const float WCA[5] = {0.46875f, 0.96875f, 0.96875f, 0.96875f, 0.96875f};
    const float WCB[5] = {0.03125f, 0.03125f, 0.03125f, 0.03125f, 0.53125f};

    float bmax = -1e30f, bmin = 1e30f;
    int bmaxi = 0, bmini = 0;
#pragma unroll
    for (int sy = 0; sy < 5; ++sy) {
#pragma unroll
        for (int e = 0; e < 2; ++e) {
            int r = e ? L1[sy] : L0[sy];      // corner row (cell-local)
            int oy = cy * 64 + r;
            float fy = (oy + 0.5f) * 0.0625f - 0.5f;  // exact dyadic
            float y0f = floorf(fy);
            float wy = fy - y0f, w1y = 1.0f - wy;
            bool ylo = fy < 0.0f, yhi = fy > 63.0f;
            int y0 = (int)y0f;
            const float* P0 = S + min(max(y0, 0), 63) * 65;
            const float* P1 = S + min(max(y0 + 1, 0), 63) * 65;
            float qv[6];
#pragma unroll
            for (int j = 0; j < 6; ++j) {
                float a = P0[gxs[j]], c = P1[gxs[j]];
                qv[j] = ylo ? a : (yhi ? c : w1y * a + wy * c);
            }
#pragma unroll
            for (int s5 = 0; s5 < 5; ++s5) {
                float q0 = qv[s5], q1 = qv[s5 + 1];
                float va, vb;
                if (cx == 0 && s5 == 0)       { va = q1; vb = q1; }  // fx<0 single tap
                else if (cx == 15 && s5 == 4) { va = q0; vb = q0; }  // fx>63 single tap
                else {
                    va = WCA[s5] * q0 + WXA[s5] * q1;
                    vb = WCB[s5] * q0 + WXB[s5] * q1;
                }
                float smax, smin; int smaxl, sminl;
                if (va >= vb) { smax = va; smaxl = L0[s5]; } else { smax = vb; smaxl = L1[s5]; }
                if (va <= vb) { smin = va; sminl = L0[s5]; } else { smin = vb; sminl = L1[s5]; }
                if (smax > bmax) { bmax = smax; bmaxi = r * 64 + smaxl; }
                if (smin < bmin) { bmin = smin; bmini = oy * 1024 + cx * 64 + sminl; }
            }
        }
    }

    // --- threshold + stable descending rank sort (block = whole map) ---
    bool valid = bmax > THRESH;
    float px = valid ? (float)(cx * 64 + (bmaxi & 63)) : -1.0f;
    float py = valid ? (float)(cy * 64 + (bmaxi >> 6)) : -1.0f;
    float ps = valid ? bmax : -1.0f;
    sc[t] = ps;
    __syncthreads();
    int rank = 0;
    const f4* sc4 = (const f4*)sc;
#pragma unroll 8
    for (int j4 = 0; j4 < 64; ++j4) {
        f4 s4 = sc4[j4];
        int j = j4 * 4;
        rank += (s4.x > ps || (s4.x == ps && (j + 0) < t)) ? 1 : 0;
        rank += (s4.y > ps || (s4.y == ps && (j + 1) < t)) ? 1 : 0;
        rank += (s4.z > ps || (s4.z == ps && (j + 2) < t)) ? 1 : 0;
        rank += (s4.w > ps || (s4.w == ps && (j + 3) < t)) ? 1 : 0;
    }
    float* o = out + m * 768 + rank * 3;
    o[0] = px; o[1] = py; o[2] = ps;

    // --- bg argmin: wave reduce + cross-wave merge; lower flat idx wins ties ---
    for (int off = 32; off > 0; off >>= 1) {
        float mv = __shfl_down(bmin, off);
        int   mj = __shfl_down(bmini, off);
        if (mv < bmin || (mv == bmin && mj < bmini)) { bmin = mv; bmini = mj; }
    }
    if ((t & 63) == 0) { wmin[t >> 6] = bmin; wmini[t >> 6] = bmini; }
    __syncthreads();
    if (t == 0) {
        float bv = wmin[0]; int bi = wmini[0];
        for (int w = 1; w < 4; ++w) {
            if (wmin[w] < bv || (wmin[w] == bv && wmini[w] < bi)) {
                bv = wmin[w]; bi = wmini[w];
            }
        }
        out[24576 + m * 2 + 0] = (float)(bi % 1024);  // x = col
        out[24576 + m * 2 + 1] = (float)(bi / 1024);  // y = row
    }
}

extern "C" void kernel_launch(void* const* d_in, const int* in_sizes, int n_in,
                              void* d_out, int out_size, void* d_ws, size_t ws_size,
                              hipStream_t stream) {
    const float* feat = (const float*)d_in[0];  // (1,256,64,64)
    const float* ref  = (const float*)d_in[1];  // (32,1,256)
    if (in_sizes[0] == 32 * 256) {  // defensive: swap if order reversed
        feat = (const float*)d_in[1];
        ref  = (const float*)d_in[0];
    }
    float* out = (float*)d_out;
    float* sim = (float*)d_ws;

    k_sim<<<dim3(32, 16), 256, 0, stream>>>(feat, ref, sim);
    k_scan_out<<<32, 256, 0, stream>>>(sim, out);
}